// Round 9
// baseline (273.576 us; speedup 1.0000x reference)
//
#include <hip/hip_runtime.h>
#include <stdint.h>

typedef unsigned short u16;
typedef __bf16 bf16;
typedef bf16 bf16x8 __attribute__((ext_vector_type(8)));
typedef float f32x4 __attribute__((ext_vector_type(4)));
typedef u16 u16x8 __attribute__((ext_vector_type(8)));
typedef u16 u16x4 __attribute__((ext_vector_type(4)));

#define T_SEQ 2048
#define NHEAD 16
#define HD    64
#define CEMB  1024
#define QS    8388608   // elems per q/k/v tensor: 4*16*2048*64
#define QSCALE 0.18033688011112042f   // 0.125 * log2(e); softmax in exp2 domain

__device__ __forceinline__ u16 f2b(float f){
  bf16 h = (bf16)f;
  return __builtin_bit_cast(u16, h);
}
__device__ __forceinline__ void glds16(const void* g, const void* l){
  __builtin_amdgcn_global_load_lds(
    (__attribute__((address_space(1))) unsigned int*)(uintptr_t)g,
    (__attribute__((address_space(3))) unsigned int*)(uintptr_t)l,
    16, 0, 0);
}

// -------- fused prep: x fp32->bf16 (4096 blocks), W_attn T (768), W_proj T (256)
__global__ __launch_bounds__(256) void prep_kernel(
    const float* __restrict__ x, u16* __restrict__ xb,
    const float* __restrict__ Wa, u16* __restrict__ Wta,
    const float* __restrict__ Wp, u16* __restrict__ Wtp)
{
  __shared__ __align__(16) u16 tile[64][72];
  const int bid = blockIdx.x;
  const int tid = threadIdx.x;
  if (bid < 4096){
    const int i = (bid * 256 + tid) * 8;
    f32x4 a = *(const f32x4*)&x[i];
    f32x4 b = *(const f32x4*)&x[i + 4];
    u16x8 h;
    #pragma unroll
    for (int j = 0; j < 4; j++){ h[j] = f2b(a[j]); h[4+j] = f2b(b[j]); }
    *(u16x8*)&xb[i] = h;
    return;
  }
  const float* src; u16* dst; int K, N, bx, by;
  if (bid < 4864){ const int j = bid - 4096; src = Wa; dst = Wta; K = 1024; N = 3072; bx = j % 48; by = j / 48; }
  else           { const int j = bid - 4864; src = Wp; dst = Wtp; K = 1024; N = 1024; bx = j % 16; by = j / 16; }
  const int n0 = bx * 64, k0 = by * 64;
  #pragma unroll
  for (int it = 0; it < 4; it++){
    const int idx = it * 256 + tid;
    const int row = idx >> 4, c4 = (idx & 15) * 4;
    f32x4 v = *(const f32x4*)&src[(size_t)(k0 + row) * N + n0 + c4];
    #pragma unroll
    for (int j = 0; j < 4; j++) tile[row][c4 + j] = f2b(v[j]);
  }
  __syncthreads();
  const int r = tid >> 3, cc = (tid & 7) * 8;
  #pragma unroll
  for (int i = 0; i < 2; i++){
    const int rr = r + i * 32;
    u16x8 v;
    #pragma unroll
    for (int j = 0; j < 8; j++) v[j] = tile[cc + j][rr];
    *(u16x8*)&dst[(size_t)(n0 + rr) * K + k0 + cc] = v;
  }
}

// ---------------- GEMM: A[M,K](bf16) * Bt[N,K]^T (+bias fp32) ----------------
// (round-7 proven version: D rows = tokens, cols = features)
// MODE 0: qkv scatter (bf16): q (pre-scaled by QSCALE), k -> [B,H,T,hd];
//         v -> [B,H,hd,T] transposed
// MODE 1: fp32 [M,N] row-major (d_out)
template<int MODE>
__global__ __launch_bounds__(256) void gemm_bt(
    const u16* __restrict__ A, const u16* __restrict__ Bt,
    const float* __restrict__ bias, void* __restrict__ outraw, int Ktot)
{
  __shared__ __align__(16) u16 As[128*64];
  __shared__ __align__(16) u16 Bs[128*64];
  const int tid = threadIdx.x;
  const int lane = tid & 63, wave = tid >> 6;
  const int l15 = lane & 15, l4 = lane >> 4;
  const int wm = wave >> 1, wn = wave & 1;
  const int m0 = blockIdx.y * 128, n0 = blockIdx.x * 128;

  f32x4 acc[4][4] = {};

  for (int k0 = 0; k0 < Ktot; k0 += 64){
    #pragma unroll
    for (int ii = 0; ii < 4; ii++){
      const int slot0 = (wave*4 + ii) * 64;
      const int s = slot0 + lane;
      const int row = s >> 3;
      const int c = (s & 7) ^ (row & 7);
      glds16(&A [(size_t)(m0 + row) * Ktot + k0 + c*8], &As[slot0*8]);
      glds16(&Bt[(size_t)(n0 + row) * Ktot + k0 + c*8], &Bs[slot0*8]);
    }
    __syncthreads();
    #pragma unroll
    for (int ks = 0; ks < 2; ks++){
      bf16x8 af[4], bfr[4];
      #pragma unroll
      for (int mt = 0; mt < 4; mt++){
        const int rf = wm*64 + mt*16 + l15;
        const int slot = rf*8 + ((ks*4 + l4) ^ (rf & 7));
        af[mt] = *(const bf16x8*)&As[slot*8];
      }
      #pragma unroll
      for (int nt = 0; nt < 4; nt++){
        const int rf = wn*64 + nt*16 + l15;
        const int slot = rf*8 + ((ks*4 + l4) ^ (rf & 7));
        bfr[nt] = *(const bf16x8*)&Bs[slot*8];
      }
      #pragma unroll
      for (int mt = 0; mt < 4; mt++)
        #pragma unroll
        for (int nt = 0; nt < 4; nt++)
          acc[mt][nt] = __builtin_amdgcn_mfma_f32_16x16x32_bf16(
              af[mt], bfr[nt], acc[mt][nt], 0, 0, 0);
    }
    __syncthreads();
  }

  #pragma unroll
  for (int nt = 0; nt < 4; nt++){
    const int n = n0 + wn*64 + nt*16 + l15;
    const float bias_v = bias[n];
    if (MODE == 0){
      u16* out = (u16*)outraw;
      const int which = n >> 10;
      const int cc = n & 1023;
      const int h = cc >> 6, d = cc & 63;
      const float sc = (which == 0) ? QSCALE : 1.0f;
      if (which == 2){
        #pragma unroll
        for (int mt = 0; mt < 4; mt++){
          const int rowg = m0 + wm*64 + mt*16 + l4*4;
          const int bb = rowg >> 11, t = rowg & 2047;
          u16x4 pk;
          #pragma unroll
          for (int r = 0; r < 4; r++) pk[r] = f2b(acc[mt][nt][r] + bias_v);
          *(u16x4*)&out[(size_t)2*QS + ((size_t)(bb*NHEAD + h)*HD + d)*T_SEQ + t] = pk;
        }
      } else {
        #pragma unroll
        for (int mt = 0; mt < 4; mt++)
          #pragma unroll
          for (int r = 0; r < 4; r++){
            const int rowg = m0 + wm*64 + mt*16 + l4*4 + r;
            const int bb = rowg >> 11, t = rowg & 2047;
            out[(size_t)which*QS + ((size_t)(bb*NHEAD + h)*T_SEQ + t)*HD + d]
                = f2b((acc[mt][nt][r] + bias_v) * sc);
          }
      }
    } else {
      float* out = (float*)outraw;
      #pragma unroll
      for (int mt = 0; mt < 4; mt++)
        #pragma unroll
        for (int r = 0; r < 4; r++){
          const int rowg = m0 + wm*64 + mt*16 + l4*4 + r;
          out[(size_t)rowg*CEMB + n] = acc[mt][nt][r] + bias_v;
        }
    }
  }
}

// ---------------- causal flash attention, S^T, no-max softmax ----------------
// 1024 blocks (longest qt first); 256 threads = 4 waves; 128 q per block,
// 32 q per wave in two 16-q groups sharing each K/V fragment read.
// K/V register-prefetched (full compute phase of latency hiding), staged to
// XOR-swizzled LDS via conflict-free ds_write_b128.
__global__ __launch_bounds__(256, 4) void attn_kernel(
    const u16* __restrict__ qb, const u16* __restrict__ kb,
    const u16* __restrict__ vtb, u16* __restrict__ y)
{
  __shared__ __align__(16) u16 Ks[64*64];     // swizzled
  __shared__ __align__(16) u16 Vt[64*64];     // swizzled (V^T rows [d][t])
  __shared__ __align__(16) u16 Pw[8*16*72];   // per (wave,group) P[q][t]
  const int tid = threadIdx.x;
  const int lane = tid & 63, wave = tid >> 6;
  const int l15 = lane & 15, l4 = lane >> 4;
  const int qt = 15 - (blockIdx.x >> 6);      // longest-first
  const int bh = blockIdx.x & 63;
  const int q0 = qt * 128;
  const size_t base = (size_t)bh * (T_SEQ * HD);
  const u16* qp  = qb  + base;
  const u16* kp  = kb  + base;
  const u16* vtp = vtb + base;                // [hd][T]

  const int qmin0 = q0 + wave*32;
  const int qmin1 = qmin0 + 16;

  // Q as B-operand frags for both groups
  bf16x8 qf[2][2];
  #pragma unroll
  for (int g = 0; g < 2; g++){
    const int m = qmin0 + g*16 + l15;
    qf[g][0] = *(const bf16x8*)&qp[m*HD +      l4*8];
    qf[g][1] = *(const bf16x8*)&qp[m*HD + 32 + l4*8];
  }
  f32x4 o[2][4] = {};
  float l_run[2] = {0.f, 0.f};

  // staging: thread owns LDS slots tid and tid+256; slot s holds global chunk
  // (row = s>>3, chunk col = (s&7) ^ (row&7)) — same swizzle as frag reads.
  const int sA = tid, sB = tid + 256;
  const int rowA = sA >> 3, cA = (sA & 7) ^ (rowA & 7);
  const int rowB = sB >> 3, cB = (sB & 7) ^ (rowB & 7);
  const int koffA = rowA*HD + cA*8, koffB = rowB*HD + cB*8;
  const int voffA = rowA*T_SEQ + cA*8, voffB = rowB*T_SEQ + cB*8;

  // prefetch tile 0 into registers
  u16x8 kra = *(const u16x8*)&kp [koffA];
  u16x8 krb = *(const u16x8*)&kp [koffB];
  u16x8 vra = *(const u16x8*)&vtp[voffA];
  u16x8 vrb = *(const u16x8*)&vtp[voffB];

  const int nkt = 2*qt + 2;
  for (int kt = 0; kt < nkt; kt++){
    __syncthreads();                          // prior tile's LDS reads done
    *(u16x8*)&Ks[sA*8] = kra;
    *(u16x8*)&Ks[sB*8] = krb;
    *(u16x8*)&Vt[sA*8] = vra;
    *(u16x8*)&Vt[sB*8] = vrb;
    __syncthreads();                          // LDS tile ready
    if (kt + 1 < nkt){                        // prefetch next tile (hidden by compute)
      kra = *(const u16x8*)&kp [(kt+1)*4096 + koffA];
      krb = *(const u16x8*)&kp [(kt+1)*4096 + koffB];
      vra = *(const u16x8*)&vtp[(kt+1)*64   + voffA];
      vrb = *(const u16x8*)&vtp[(kt+1)*64   + voffB];
    }

    const int t0 = kt*64;
    if (t0 <= qmin1 + 15){                    // wave-uniform
      const bool act0 = (t0 <= qmin0 + 15);

      // S^T = K·Q^T for both groups, sharing each K fragment read
      f32x4 s0[4], s1[4];
      #pragma unroll
      for (int nb = 0; nb < 4; nb++){
        f32x4 a0 = {}, a1 = {};
        #pragma unroll
        for (int ks = 0; ks < 2; ks++){
          const int rf = nb*16 + l15;
          const int slot = rf*8 + ((ks*4 + l4) ^ (rf & 7));
          bf16x8 kf = *(const bf16x8*)&Ks[slot*8];
          a1 = __builtin_amdgcn_mfma_f32_16x16x32_bf16(kf, qf[1][ks], a1, 0, 0, 0);
          if (act0)
            a0 = __builtin_amdgcn_mfma_f32_16x16x32_bf16(kf, qf[0][ks], a0, 0, 0, 0);
        }
        s1[nb] = a1; s0[nb] = a0;
      }

      // softmax (exp2 domain, no max tracking) + P write, per group
      #pragma unroll
      for (int g = 0; g < 2; g++){
        if (g == 0 && !act0) continue;
        f32x4* sf = (g == 0) ? s0 : s1;
        const int qmin = (g == 0) ? qmin0 : qmin1;
        const int qg = qmin + l15;
        float lsum = 0.f;
        if (t0 + 63 > qmin){                  // diagonal-region tile: mask
          #pragma unroll
          for (int nb = 0; nb < 4; nb++){
            u16x4 pk;
            #pragma unroll
            for (int r = 0; r < 4; r++){
              const int t = t0 + nb*16 + l4*4 + r;
              float p = __builtin_amdgcn_exp2f(sf[nb][r]);
              p = (t <= qg) ? p : 0.0f;
              lsum += p;
              pk[r] = f2b(p);
            }
            *(u16x4*)&Pw[(wave*2 + g)*1152 + l15*72 + nb*16 + l4*4] = pk;
          }
        } else {
          #pragma unroll
          for (int nb = 0; nb < 4; nb++){
            u16x4 pk;
            #pragma unroll
            for (int r = 0; r < 4; r++){
              const float p = __builtin_amdgcn_exp2f(sf[nb][r]);
              lsum += p;
              pk[r] = f2b(p);
            }
            *(u16x4*)&Pw[(wave*2 + g)*1152 + l15*72 + nb*16 + l4*4] = pk;
          }
        }
        l_run[g] += lsum;
      }

      // O^T += V^T·P^T, sharing each V fragment read between groups
      #pragma unroll
      for (int ks = 0; ks < 2; ks++){
        bf16x8 pf1 = *(const bf16x8*)&Pw[(wave*2 + 1)*1152 + l15*72 + ks*32 + l4*8];
        bf16x8 pf0;
        if (act0) pf0 = *(const bf16x8*)&Pw[(wave*2 + 0)*1152 + l15*72 + ks*32 + l4*8];
        #pragma unroll
        for (int nh = 0; nh < 4; nh++){
          const int rf = nh*16 + l15;
          const int slot = rf*8 + ((ks*4 + l4) ^ (rf & 7));
          bf16x8 vf = *(const bf16x8*)&Vt[slot*8];
          o[1][nh] = __builtin_amdgcn_mfma_f32_16x16x32_bf16(vf, pf1, o[1][nh], 0, 0, 0);
          if (act0)
            o[0][nh] = __builtin_amdgcn_mfma_f32_16x16x32_bf16(vf, pf0, o[0][nh], 0, 0, 0);
        }
      }
    }
  }

  // epilogue per group: O^T[d][q]; lane q = l15; d = nh*16 + l4*4 + r
  const int b = bh >> 4, h = bh & 15;
  #pragma unroll
  for (int g = 0; g < 2; g++){
    float lr = l_run[g];
    lr += __shfl_xor(lr, 16);
    lr += __shfl_xor(lr, 32);
    const float inv_l = 1.0f / lr;
    const int t = qmin0 + g*16 + l15;
    #pragma unroll
    for (int nh = 0; nh < 4; nh++){
      u16x4 pk;
      #pragma unroll
      for (int r = 0; r < 4; r++) pk[r] = f2b(o[g][nh][r] * inv_l);
      *(u16x4*)&y[((size_t)(b*T_SEQ + t))*CEMB + h*HD + nh*16 + l4*4] = pk;
    }
  }
}

extern "C" void kernel_launch(void* const* d_in, const int* in_sizes, int n_in,
                              void* d_out, int out_size, void* d_ws, size_t ws_size,
                              hipStream_t stream) {
  const float* x      = (const float*)d_in[0];
  const float* W_attn = (const float*)d_in[1];
  const float* b_attn = (const float*)d_in[2];
  const float* W_proj = (const float*)d_in[3];
  const float* b_proj = (const float*)d_in[4];
  float* out = (float*)d_out;
  u16* ws  = (u16*)d_ws;

  u16* Wt_attn = ws;                 // 3,145,728
  u16* Wt_proj = ws + 3145728;       // 1,048,576
  u16* xb      = ws + 4194304;       // 8,388,608 (x as bf16; reused as y)
  u16* qkv     = ws + 12582912;      // 3 * QS
  u16* y       = xb;                 // xb dead after QKV GEMM

  prep_kernel<<<5120, 256, 0, stream>>>(x, xb, W_attn, Wt_attn, W_proj, Wt_proj);
  gemm_bt<0><<<dim3(24, 64), 256, 0, stream>>>(xb, Wt_attn, b_attn, qkv, 1024);
  attn_kernel<<<1024, 256, 0, stream>>>(qkv, qkv + QS, qkv + 2*QS, y);
  gemm_bt<1><<<dim3(8, 64), 256, 0, stream>>>(y, Wt_proj, b_proj, out, 1024);
}

// Round 10
// 241.651 us; speedup vs baseline: 1.1321x; 1.1321x over previous
//
#include <hip/hip_runtime.h>
#include <stdint.h>

typedef unsigned short u16;
typedef __bf16 bf16;
typedef bf16 bf16x8 __attribute__((ext_vector_type(8)));
typedef float f32x4 __attribute__((ext_vector_type(4)));
typedef u16 u16x8 __attribute__((ext_vector_type(8)));
typedef u16 u16x4 __attribute__((ext_vector_type(4)));

#define T_SEQ 2048
#define NHEAD 16
#define HD    64
#define CEMB  1024
#define QS    8388608   // elems per q/k/v tensor: 4*16*2048*64
#define QSCALE 0.18033688011112042f   // 0.125 * log2(e); softmax in exp2 domain

__device__ __forceinline__ u16 f2b(float f){
  bf16 h = (bf16)f;
  return __builtin_bit_cast(u16, h);
}
__device__ __forceinline__ void glds16(const void* g, const void* l){
  __builtin_amdgcn_global_load_lds(
    (__attribute__((address_space(1))) unsigned int*)(uintptr_t)g,
    (__attribute__((address_space(3))) unsigned int*)(uintptr_t)l,
    16, 0, 0);
}

// -------- fused prep: x fp32->bf16 (4096 blocks), W_attn T (768), W_proj T (256)
__global__ __launch_bounds__(256) void prep_kernel(
    const float* __restrict__ x, u16* __restrict__ xb,
    const float* __restrict__ Wa, u16* __restrict__ Wta,
    const float* __restrict__ Wp, u16* __restrict__ Wtp)
{
  __shared__ __align__(16) u16 tile[64][72];
  const int bid = blockIdx.x;
  const int tid = threadIdx.x;
  if (bid < 4096){
    const int i = (bid * 256 + tid) * 8;
    f32x4 a = *(const f32x4*)&x[i];
    f32x4 b = *(const f32x4*)&x[i + 4];
    u16x8 h;
    #pragma unroll
    for (int j = 0; j < 4; j++){ h[j] = f2b(a[j]); h[4+j] = f2b(b[j]); }
    *(u16x8*)&xb[i] = h;
    return;
  }
  const float* src; u16* dst; int K, N, bx, by;
  if (bid < 4864){ const int j = bid - 4096; src = Wa; dst = Wta; K = 1024; N = 3072; bx = j % 48; by = j / 48; }
  else           { const int j = bid - 4864; src = Wp; dst = Wtp; K = 1024; N = 1024; bx = j % 16; by = j / 16; }
  const int n0 = bx * 64, k0 = by * 64;
  #pragma unroll
  for (int it = 0; it < 4; it++){
    const int idx = it * 256 + tid;
    const int row = idx >> 4, c4 = (idx & 15) * 4;
    f32x4 v = *(const f32x4*)&src[(size_t)(k0 + row) * N + n0 + c4];
    #pragma unroll
    for (int j = 0; j < 4; j++) tile[row][c4 + j] = f2b(v[j]);
  }
  __syncthreads();
  const int r = tid >> 3, cc = (tid & 7) * 8;
  #pragma unroll
  for (int i = 0; i < 2; i++){
    const int rr = r + i * 32;
    u16x8 v;
    #pragma unroll
    for (int j = 0; j < 8; j++) v[j] = tile[cc + j][rr];
    *(u16x8*)&dst[(size_t)(n0 + rr) * K + k0 + cc] = v;
  }
}

// ---------------- GEMM: A[M,K](bf16) * Bt[N,K]^T (+bias fp32) ----------------
// (round-7 proven version: D rows = tokens, cols = features)
// MODE 0: qkv scatter (bf16): q (pre-scaled by QSCALE), k -> [B,H,T,hd];
//         v -> [B,H,hd,T] transposed
// MODE 1: fp32 [M,N] row-major (d_out)
template<int MODE>
__global__ __launch_bounds__(256) void gemm_bt(
    const u16* __restrict__ A, const u16* __restrict__ Bt,
    const float* __restrict__ bias, void* __restrict__ outraw, int Ktot)
{
  __shared__ __align__(16) u16 As[128*64];
  __shared__ __align__(16) u16 Bs[128*64];
  const int tid = threadIdx.x;
  const int lane = tid & 63, wave = tid >> 6;
  const int l15 = lane & 15, l4 = lane >> 4;
  const int wm = wave >> 1, wn = wave & 1;
  const int m0 = blockIdx.y * 128, n0 = blockIdx.x * 128;

  f32x4 acc[4][4] = {};

  for (int k0 = 0; k0 < Ktot; k0 += 64){
    #pragma unroll
    for (int ii = 0; ii < 4; ii++){
      const int slot0 = (wave*4 + ii) * 64;
      const int s = slot0 + lane;
      const int row = s >> 3;
      const int c = (s & 7) ^ (row & 7);
      glds16(&A [(size_t)(m0 + row) * Ktot + k0 + c*8], &As[slot0*8]);
      glds16(&Bt[(size_t)(n0 + row) * Ktot + k0 + c*8], &Bs[slot0*8]);
    }
    __syncthreads();
    #pragma unroll
    for (int ks = 0; ks < 2; ks++){
      bf16x8 af[4], bfr[4];
      #pragma unroll
      for (int mt = 0; mt < 4; mt++){
        const int rf = wm*64 + mt*16 + l15;
        const int slot = rf*8 + ((ks*4 + l4) ^ (rf & 7));
        af[mt] = *(const bf16x8*)&As[slot*8];
      }
      #pragma unroll
      for (int nt = 0; nt < 4; nt++){
        const int rf = wn*64 + nt*16 + l15;
        const int slot = rf*8 + ((ks*4 + l4) ^ (rf & 7));
        bfr[nt] = *(const bf16x8*)&Bs[slot*8];
      }
      #pragma unroll
      for (int mt = 0; mt < 4; mt++)
        #pragma unroll
        for (int nt = 0; nt < 4; nt++)
          acc[mt][nt] = __builtin_amdgcn_mfma_f32_16x16x32_bf16(
              af[mt], bfr[nt], acc[mt][nt], 0, 0, 0);
    }
    __syncthreads();
  }

  #pragma unroll
  for (int nt = 0; nt < 4; nt++){
    const int n = n0 + wn*64 + nt*16 + l15;
    const float bias_v = bias[n];
    if (MODE == 0){
      u16* out = (u16*)outraw;
      const int which = n >> 10;
      const int cc = n & 1023;
      const int h = cc >> 6, d = cc & 63;
      const float sc = (which == 0) ? QSCALE : 1.0f;
      if (which == 2){
        #pragma unroll
        for (int mt = 0; mt < 4; mt++){
          const int rowg = m0 + wm*64 + mt*16 + l4*4;
          const int bb = rowg >> 11, t = rowg & 2047;
          u16x4 pk;
          #pragma unroll
          for (int r = 0; r < 4; r++) pk[r] = f2b(acc[mt][nt][r] + bias_v);
          *(u16x4*)&out[(size_t)2*QS + ((size_t)(bb*NHEAD + h)*HD + d)*T_SEQ + t] = pk;
        }
      } else {
        #pragma unroll
        for (int mt = 0; mt < 4; mt++)
          #pragma unroll
          for (int r = 0; r < 4; r++){
            const int rowg = m0 + wm*64 + mt*16 + l4*4 + r;
            const int bb = rowg >> 11, t = rowg & 2047;
            out[(size_t)which*QS + ((size_t)(bb*NHEAD + h)*T_SEQ + t)*HD + d]
                = f2b((acc[mt][nt][r] + bias_v) * sc);
          }
      }
    } else {
      float* out = (float*)outraw;
      #pragma unroll
      for (int mt = 0; mt < 4; mt++)
        #pragma unroll
        for (int r = 0; r < 4; r++){
          const int rowg = m0 + wm*64 + mt*16 + l4*4 + r;
          out[(size_t)rowg*CEMB + n] = acc[mt][nt][r] + bias_v;
        }
    }
  }
}

// ---------------- causal flash attention, S^T, no-max softmax ----------------
// 1024 blocks (longest qt first); 256 threads = 4 waves; 128 q per block,
// 32 q per wave in two 16-q groups sharing each K/V fragment read.
// K/V staged via glds16 into DOUBLE-BUFFERED swizzled LDS, single barrier per
// tile: the vmcnt drain before each barrier lands AFTER a full compute phase.
__global__ __launch_bounds__(256, 3) void attn_kernel(
    const u16* __restrict__ qb, const u16* __restrict__ kb,
    const u16* __restrict__ vtb, u16* __restrict__ y)
{
  __shared__ __align__(16) u16 Ks[2][64*64];  // swizzled, double-buffered
  __shared__ __align__(16) u16 Vt[2][64*64];  // swizzled (V^T rows [d][t])
  __shared__ __align__(16) u16 Pw[8*16*72];   // per (wave,group) P[q][t]
  const int tid = threadIdx.x;
  const int lane = tid & 63, wave = tid >> 6;
  const int l15 = lane & 15, l4 = lane >> 4;
  const int qt = 15 - (blockIdx.x >> 6);      // longest-first
  const int bh = blockIdx.x & 63;
  const int q0 = qt * 128;
  const size_t base = (size_t)bh * (T_SEQ * HD);
  const u16* qp  = qb  + base;
  const u16* kp  = kb  + base;
  const u16* vtp = vtb + base;                // [hd][T]

  const int qmin0 = q0 + wave*32;
  const int qmin1 = qmin0 + 16;

  // Q as B-operand frags for both groups
  bf16x8 qf[2][2];
  #pragma unroll
  for (int g = 0; g < 2; g++){
    const int m = qmin0 + g*16 + l15;
    qf[g][0] = *(const bf16x8*)&qp[m*HD +      l4*8];
    qf[g][1] = *(const bf16x8*)&qp[m*HD + 32 + l4*8];
  }
  f32x4 o[2][4] = {};
  float l_run[2] = {0.f, 0.f};

  // staging addresses (constant per thread): 2 chunks each for K and V
  const int s0i = (wave*2 + 0) * 64 + lane;
  const int s1i = (wave*2 + 1) * 64 + lane;
  const int row0 = s0i >> 3, c0 = (s0i & 7) ^ (row0 & 7);
  const int row1 = s1i >> 3, c1 = (s1i & 7) ^ (row1 & 7);
  const int koff0 = row0*HD + c0*8, koff1 = row1*HD + c1*8;
  const int voff0 = row0*T_SEQ + c0*8, voff1 = row1*T_SEQ + c1*8;
  const int ldso0 = (wave*2 + 0) * 64 * 8, ldso1 = (wave*2 + 1) * 64 * 8;

  // issue tile 0 into buffer 0
  glds16(&kp [koff0], &Ks[0][ldso0]);
  glds16(&kp [koff1], &Ks[0][ldso1]);
  glds16(&vtp[voff0], &Vt[0][ldso0]);
  glds16(&vtp[voff1], &Vt[0][ldso1]);

  const int nkt = 2*qt + 2;
  for (int kt = 0; kt < nkt; kt++){
    const int cb = kt & 1, nb2 = cb ^ 1;
    __syncthreads();   // drains vmcnt: tile kt landed; prior reads of buf nb2 done
    if (kt + 1 < nkt){ // issue next tile; lands during compute below
      glds16(&kp [(kt+1)*4096 + koff0], &Ks[nb2][ldso0]);
      glds16(&kp [(kt+1)*4096 + koff1], &Ks[nb2][ldso1]);
      glds16(&vtp[(kt+1)*64   + voff0], &Vt[nb2][ldso0]);
      glds16(&vtp[(kt+1)*64   + voff1], &Vt[nb2][ldso1]);
    }

    const int t0 = kt*64;
    if (t0 <= qmin1 + 15){                    // wave-uniform
      const bool act0 = (t0 <= qmin0 + 15);

      // S^T = K·Q^T for both groups, sharing each K fragment read
      f32x4 s0[4], s1[4];
      #pragma unroll
      for (int nb = 0; nb < 4; nb++){
        f32x4 a0 = {}, a1 = {};
        #pragma unroll
        for (int ks = 0; ks < 2; ks++){
          const int rf = nb*16 + l15;
          const int slot = rf*8 + ((ks*4 + l4) ^ (rf & 7));
          bf16x8 kf = *(const bf16x8*)&Ks[cb][slot*8];
          a1 = __builtin_amdgcn_mfma_f32_16x16x32_bf16(kf, qf[1][ks], a1, 0, 0, 0);
          if (act0)
            a0 = __builtin_amdgcn_mfma_f32_16x16x32_bf16(kf, qf[0][ks], a0, 0, 0, 0);
        }
        s1[nb] = a1; s0[nb] = a0;
      }

      // softmax (exp2 domain, no max tracking) + P write, per group
      #pragma unroll
      for (int g = 0; g < 2; g++){
        if (g == 0 && !act0) continue;
        f32x4* sf = (g == 0) ? s0 : s1;
        const int qmin = (g == 0) ? qmin0 : qmin1;
        const int qg = qmin + l15;
        float lsum = 0.f;
        if (t0 + 63 > qmin){                  // diagonal-region tile: mask
          #pragma unroll
          for (int nb = 0; nb < 4; nb++){
            u16x4 pk;
            #pragma unroll
            for (int r = 0; r < 4; r++){
              const int t = t0 + nb*16 + l4*4 + r;
              float p = __builtin_amdgcn_exp2f(sf[nb][r]);
              p = (t <= qg) ? p : 0.0f;
              lsum += p;
              pk[r] = f2b(p);
            }
            *(u16x4*)&Pw[(wave*2 + g)*1152 + l15*72 + nb*16 + l4*4] = pk;
          }
        } else {
          #pragma unroll
          for (int nb = 0; nb < 4; nb++){
            u16x4 pk;
            #pragma unroll
            for (int r = 0; r < 4; r++){
              const float p = __builtin_amdgcn_exp2f(sf[nb][r]);
              lsum += p;
              pk[r] = f2b(p);
            }
            *(u16x4*)&Pw[(wave*2 + g)*1152 + l15*72 + nb*16 + l4*4] = pk;
          }
        }
        l_run[g] += lsum;
      }

      // O^T += V^T·P^T, sharing each V fragment read between groups
      #pragma unroll
      for (int ks = 0; ks < 2; ks++){
        bf16x8 pf1 = *(const bf16x8*)&Pw[(wave*2 + 1)*1152 + l15*72 + ks*32 + l4*8];
        bf16x8 pf0;
        if (act0) pf0 = *(const bf16x8*)&Pw[(wave*2 + 0)*1152 + l15*72 + ks*32 + l4*8];
        #pragma unroll
        for (int nh = 0; nh < 4; nh++){
          const int rf = nh*16 + l15;
          const int slot = rf*8 + ((ks*4 + l4) ^ (rf & 7));
          bf16x8 vf = *(const bf16x8*)&Vt[cb][slot*8];
          o[1][nh] = __builtin_amdgcn_mfma_f32_16x16x32_bf16(vf, pf1, o[1][nh], 0, 0, 0);
          if (act0)
            o[0][nh] = __builtin_amdgcn_mfma_f32_16x16x32_bf16(vf, pf0, o[0][nh], 0, 0, 0);
        }
      }
    }
  }

  // epilogue per group: O^T[d][q]; lane q = l15; d = nh*16 + l4*4 + r
  const int b = bh >> 4, h = bh & 15;
  #pragma unroll
  for (int g = 0; g < 2; g++){
    float lr = l_run[g];
    lr += __shfl_xor(lr, 16);
    lr += __shfl_xor(lr, 32);
    const float inv_l = 1.0f / lr;
    const int t = qmin0 + g*16 + l15;
    #pragma unroll
    for (int nh = 0; nh < 4; nh++){
      u16x4 pk;
      #pragma unroll
      for (int r = 0; r < 4; r++) pk[r] = f2b(o[g][nh][r] * inv_l);
      *(u16x4*)&y[((size_t)(b*T_SEQ + t))*CEMB + h*HD + nh*16 + l4*4] = pk;
    }
  }
}

extern "C" void kernel_launch(void* const* d_in, const int* in_sizes, int n_in,
                              void* d_out, int out_size, void* d_ws, size_t ws_size,
                              hipStream_t stream) {
  const float* x      = (const float*)d_in[0];
  const float* W_attn = (const float*)d_in[1];
  const float* b_attn = (const float*)d_in[2];
  const float* W_proj = (const float*)d_in[3];
  const float* b_proj = (const float*)d_in[4];
  float* out = (float*)d_out;
  u16* ws  = (u16*)d_ws;

  u16* Wt_attn = ws;                 // 3,145,728
  u16* Wt_proj = ws + 3145728;       // 1,048,576
  u16* xb      = ws + 4194304;       // 8,388,608 (x as bf16; reused as y)
  u16* qkv     = ws + 12582912;      // 3 * QS
  u16* y       = xb;                 // xb dead after QKV GEMM

  prep_kernel<<<5120, 256, 0, stream>>>(x, xb, W_attn, Wt_attn, W_proj, Wt_proj);
  gemm_bt<0><<<dim3(24, 64), 256, 0, stream>>>(xb, Wt_attn, b_attn, qkv, 1024);
  attn_kernel<<<1024, 256, 0, stream>>>(qkv, qkv + QS, qkv + 2*QS, y);
  gemm_bt<1><<<dim3(8, 64), 256, 0, stream>>>(y, Wt_proj, b_proj, out, 1024);
}